// Round 2
// baseline (89.918 us; speedup 1.0000x reference)
//
#include <hip/hip_runtime.h>
#include <cstdint>
#include <cstddef>

#define NB 512
#define NL 32
#define KD 512    // P*D
#define HKD 256   // k-half per pass

// swizzled float-offset of chunk ch (4 floats) of row `row` in a [32][256] pass buffer.
__device__ __forceinline__ int swz_off(int row, int ch) {
  int csw = (ch & ~15) | ((ch ^ (row >> 1)) & 15);
  return row * HKD + csw * 4;
}

__device__ __forceinline__ double wave_min64d(double x) {
#pragma unroll
  for (int off = 32; off; off >>= 1) x = fmin(x, __shfl_xor(x, off));
  return x;
}

__global__ __launch_bounds__(256, 2)
void hungarian_loss_kernel(const float* __restrict__ pred,
                           const float* __restrict__ prob,
                           const float* __restrict__ tgt,
                           const float* __restrict__ lmask,
                           const int* __restrict__ clf,
                           float* __restrict__ part) {
  __shared__ float smem[16384];   // 64 KB: staging (2x 32x256), later aliased by cost[32][32]
  const int b = blockIdx.x;
  const int tid = threadIdx.x;

  float* predH = smem;
  float* tgtH  = smem + 8192;

  const int ti = tid >> 4, tj = tid & 15;   // 16x16 thread grid of 2x2 output tiles
  const int ia = ti * 2, ja = tj * 2;
  float acc00 = 0.f, acc01 = 0.f, acc10 = 0.f, acc11 = 0.f;

  for (int hp = 0; hp < 2; ++hp) {
    __syncthreads();  // protect LDS before re-staging (pass 1)
    const size_t base = (size_t)b * (NL * KD) + (size_t)hp * HKD;
#pragma unroll
    for (int it = 0; it < 8; ++it) {
      int chunk = tid + it * 256;            // 0..2047 -> row, chunk-in-row
      int row = chunk >> 6, ch = chunk & 63;
      const float4 pv = *reinterpret_cast<const float4*>(pred + base + (size_t)row * KD + ch * 4);
      const float4 tv = *reinterpret_cast<const float4*>(tgt  + base + (size_t)row * KD + ch * 4);
      int l = swz_off(row, ch);
      *reinterpret_cast<float4*>(predH + l) = pv;
      *reinterpret_cast<float4*>(tgtH  + l) = tv;
    }
    __syncthreads();
#pragma unroll 4
    for (int c = 0; c < 64; ++c) {
      const float4 pa = *reinterpret_cast<const float4*>(predH + swz_off(ia, c));
      const float4 pb = *reinterpret_cast<const float4*>(predH + swz_off(ia + 1, c));
      const float4 ta = *reinterpret_cast<const float4*>(tgtH + swz_off(ja, c));
      const float4 tb = *reinterpret_cast<const float4*>(tgtH + swz_off(ja + 1, c));
      float d;
      d = pa.x - ta.x; acc00 += d * d; d = pa.y - ta.y; acc00 += d * d;
      d = pa.z - ta.z; acc00 += d * d; d = pa.w - ta.w; acc00 += d * d;
      d = pa.x - tb.x; acc01 += d * d; d = pa.y - tb.y; acc01 += d * d;
      d = pa.z - tb.z; acc01 += d * d; d = pa.w - tb.w; acc01 += d * d;
      d = pb.x - ta.x; acc10 += d * d; d = pb.y - ta.y; acc10 += d * d;
      d = pb.z - ta.z; acc10 += d * d; d = pb.w - ta.w; acc10 += d * d;
      d = pb.x - tb.x; acc11 += d * d; d = pb.y - tb.y; acc11 += d * d;
      d = pb.z - tb.z; acc11 += d * d; d = pb.w - tb.w; acc11 += d * d;
    }
  }
  __syncthreads();           // all staging reads done; safe to overwrite with cost
  float* cost = smem;        // [32][32]
  cost[ia * 32 + ja]           = acc00;
  cost[ia * 32 + ja + 1]       = acc01;
  cost[(ia + 1) * 32 + ja]     = acc10;
  cost[(ia + 1) * 32 + ja + 1] = acc11;
  __syncthreads();

  if (tid < 64) {            // wave 0: n, clf partial, "hungarian" (reference-faithful), gather
    const int lane = tid;
    float lm = (lane < 32) ? lmask[b * 32 + lane] : 0.f;
    const int n = __popcll(__ballot(lm > 0.5f));
    float clfpart = 0.f;
    if (lane < 32 && lm > 0.5f) {
      int c = clf[b * 32 + lane];
      clfpart = -logf(prob[(size_t)(b * 32 + lane) * 2 + c]);
    }

    const double DINF = 1e300;
    const bool activecol = (lane >= 1 && lane <= n);
    const int cl = activecol ? lane : 1;            // clamped column index for LDS reads

    // Reference-faithful broken JV: minv/way are never persisted in the python
    // (m1/w1 are unsaved copies), so each inner step is a fresh argmin of the
    // CURRENT row's reduced costs, and the "augment" collapses to p[j_final]=i.
    // lane r holds u[r] (f64); lane j holds v[j] (f64), used[j], p[j].
    double u_r = 0.0, v_j = 0.0;
    int p_j = 0;

    for (int i = 1; i <= n; ++i) {
      if (lane == 0) p_j = i;                       // p[0] = i
      int j0 = 0;
      bool used = false;                            // column-used flag (this outer iter)
      bool row_used = false;                        // row in {i} ∪ {p[j]: j used}
      while (true) {
        used = used || (lane == j0);                // used[j0] = True
        int i0 = __shfl(p_j, j0);                   // i0 = p[j0]  (>=1 always)
        row_used = row_used || (lane == i0);
        float cst = cost[(i0 - 1) * 32 + (cl - 1)]; // row read + broadcast
        double u0 = __shfl(u_r, i0);                // pre-update u[i0]
        double cur = (double)cst - u0 - v_j;
        bool act = activecol && !used;
        double m = act ? cur : DINF;
        double delta = wave_min64d(m);
        uint64_t tie = __ballot(act && (m == delta));
        int j1 = __ffsll((unsigned long long)tie) - 1;  // numpy argmin first-index tie-break
        if (row_used) u_r += delta;                 // u[p[used]] += delta
        if (used) v_j -= delta;                     // v[used] -= delta
        j0 = j1;
        int pj1 = __shfl(p_j, j1);
        if (pj1 == 0) {                             // p[j0]==0 -> break; way==0 => p[j0]=p[0]=i
          if (lane == j1) p_j = i;
          break;
        }
      }
    }

    // assigned cost sum: column j matched to row p[j]  ->  cost[p[j]-1][j-1]
    int pj = p_j < 1 ? 1 : p_j;
    float a = activecol ? cost[(pj - 1) * 32 + (cl - 1)] : 0.f;
#pragma unroll
    for (int off = 32; off; off >>= 1) {
      a += __shfl_xor(a, off);
      clfpart += __shfl_xor(clfpart, off);
    }
    if (lane == 0) {
      part[b * 3 + 0] = a;
      part[b * 3 + 1] = clfpart;
      part[b * 3 + 2] = (float)n;
    }
  }
}

__global__ void finalize_kernel(const float* __restrict__ part, float* __restrict__ out) {
  const int lane = threadIdx.x;   // 64 threads, 1 block: deterministic fixed-order reduce
  double cs = 0.0, ls = 0.0, ns = 0.0;
  for (int i = lane; i < NB; i += 64) {
    cs += (double)part[i * 3 + 0];
    ls += (double)part[i * 3 + 1];
    ns += (double)part[i * 3 + 2];
  }
#pragma unroll
  for (int off = 32; off; off >>= 1) {
    cs += __shfl_xor(cs, off);
    ls += __shfl_xor(ls, off);
    ns += __shfl_xor(ns, off);
  }
  if (lane == 0) {
    out[0] = (float)(cs / (ns * 256.0));  // / sum(point_masks) = 256 * sum(n)
    out[1] = (float)(ls / ns);            // / sum(line_masks)
  }
}

extern "C" void kernel_launch(void* const* d_in, const int* in_sizes, int n_in,
                              void* d_out, int out_size, void* d_ws, size_t ws_size,
                              hipStream_t stream) {
  const float* pred = (const float*)d_in[0];   // point_pos_pred [512,32,256,2] f32
  const float* prob = (const float*)d_in[1];   // line_prob_pred [512,32,2] f32
  const float* tgt  = (const float*)d_in[2];   // target_pos [512,32,256,2] f32
  const float* lm   = (const float*)d_in[3];   // line_masks [512,32] f32
  const int*   clf  = (const int*)d_in[4];     // clf_line [512,32] i32
  float* part = (float*)d_ws;                  // [512][3] f32 partials

  hungarian_loss_kernel<<<NB, 256, 0, stream>>>(pred, prob, tgt, lm, clf, part);
  finalize_kernel<<<1, 64, 0, stream>>>(part, (float*)d_out);
}

// Round 3
// 81.170 us; speedup vs baseline: 1.1078x; 1.1078x over previous
//
#include <hip/hip_runtime.h>
#include <cstdint>
#include <cstddef>

#define NB 512
#define NL 32
#define KD 512    // P*D
#define HKD 256   // k-half per pass

// swizzled float-offset of chunk ch (4 floats) of row `row` in a [32][256] pass buffer.
__device__ __forceinline__ int swz_off(int row, int ch) {
  int csw = (ch & ~15) | ((ch ^ (row >> 1)) & 15);
  return row * HKD + csw * 4;
}

// one DPP min step: combine x with dpp-moved x (masked-off lanes keep x -> no-op)
template<int CTRL, int RM>
__device__ __forceinline__ float dppmin(float x) {
  int m = __builtin_amdgcn_update_dpp(__float_as_int(x), __float_as_int(x), CTRL, RM, 0xf, false);
  return fminf(x, __int_as_float(m));
}

// full-wave (64-lane) min via DPP cascade; result broadcast through SGPR.
__device__ __forceinline__ float wave_min_bcast(float x) {
  x = dppmin<0xB1, 0xf>(x);   // quad_perm [1,0,3,2]  (xor1)
  x = dppmin<0x4E, 0xf>(x);   // quad_perm [2,3,0,1]  (xor2)
  x = dppmin<0x124, 0xf>(x);  // row_ror:4
  x = dppmin<0x128, 0xf>(x);  // row_ror:8  -> all lanes hold their row16 min
  x = dppmin<0x142, 0xa>(x);  // row_bcast:15 -> rows 1,3 combine row0/row2 mins
  x = dppmin<0x143, 0xc>(x);  // row_bcast:31 -> rows 2,3 combine -> lane 63 = global min
  return __int_as_float(__builtin_amdgcn_readlane(__float_as_int(x), 63));
}

__global__ __launch_bounds__(256, 2)
void hungarian_loss_kernel(const float* __restrict__ pred,
                           const float* __restrict__ prob,
                           const float* __restrict__ tgt,
                           const float* __restrict__ lmask,
                           const int* __restrict__ clf,
                           float* __restrict__ part) {
  __shared__ float smem[16384];   // 64 KB: staging (2x 32x256); later partials + cost
  const int b = blockIdx.x;
  const int tid = threadIdx.x;

  float* predH = smem;
  float* tgtH  = smem + 8192;

  // split-K: wave w owns a 64-float k-slice of each 256-float pass; 8x8 lanes of 4x4 tiles
  const int w = tid >> 6, l = tid & 63;
  const int ti = l >> 3, tj = l & 7;
  float acc[4][4];
#pragma unroll
  for (int a = 0; a < 4; ++a)
#pragma unroll
    for (int c2 = 0; c2 < 4; ++c2) acc[a][c2] = 0.f;

  for (int hp = 0; hp < 2; ++hp) {
    __syncthreads();  // protect LDS before re-staging
    const size_t base = (size_t)b * (NL * KD) + (size_t)hp * HKD;
#pragma unroll
    for (int it = 0; it < 8; ++it) {
      int chunk = tid + it * 256;            // 0..2047 -> row, chunk-in-row
      int row = chunk >> 6, ch = chunk & 63;
      const float4 pv = *reinterpret_cast<const float4*>(pred + base + (size_t)row * KD + ch * 4);
      const float4 tv = *reinterpret_cast<const float4*>(tgt  + base + (size_t)row * KD + ch * 4);
      int off = swz_off(row, ch);
      *reinterpret_cast<float4*>(predH + off) = pv;
      *reinterpret_cast<float4*>(tgtH  + off) = tv;
    }
    __syncthreads();
#pragma unroll
    for (int c0 = 0; c0 < 16; ++c0) {
      const int c = (w << 4) + c0;
      float4 pr[4], tg[4];
#pragma unroll
      for (int r = 0; r < 4; ++r) {
        pr[r] = *reinterpret_cast<const float4*>(predH + swz_off(4 * ti + r, c));
        tg[r] = *reinterpret_cast<const float4*>(tgtH  + swz_off(4 * tj + r, c));
      }
#pragma unroll
      for (int a = 0; a < 4; ++a)
#pragma unroll
        for (int c2 = 0; c2 < 4; ++c2) {
          float d;
          d = pr[a].x - tg[c2].x; acc[a][c2] += d * d;
          d = pr[a].y - tg[c2].y; acc[a][c2] += d * d;
          d = pr[a].z - tg[c2].z; acc[a][c2] += d * d;
          d = pr[a].w - tg[c2].w; acc[a][c2] += d * d;
        }
    }
  }
  __syncthreads();           // all staging reads done; reuse LDS
  // partials at smem[o*4 + w], o = output index
#pragma unroll
  for (int a = 0; a < 4; ++a)
#pragma unroll
    for (int c2 = 0; c2 < 4; ++c2) {
      int o = (4 * ti + a) * 32 + 4 * tj + c2;
      smem[o * 4 + w] = acc[a][c2];
    }
  __syncthreads();
  float* costL = smem + 8192;  // [32][32] final cost
#pragma unroll
  for (int k = 0; k < 4; ++k) {
    int o = tid * 4 + k;
    const float4 pp = *reinterpret_cast<const float4*>(smem + o * 4);
    costL[o] = (pp.x + pp.y) + (pp.z + pp.w);
  }
  __syncthreads();

  if (tid < 64) {            // wave 0: n, clf partial, reference-faithful greedy walk, gather
    const int lane = tid;
    float lm = (lane < 32) ? lmask[b * 32 + lane] : 0.f;
    const int n = __popcll(__ballot(lm > 0.5f));
    float clfpart = 0.f;
    if (lane < 32 && lm > 0.5f) {
      int c = clf[b * 32 + lane];
      clfpart = -logf(prob[(size_t)(b * 32 + lane) * 2 + c]);
    }

    const float FINF = 1e30f;
    const bool activecol = (lane >= 1 && lane <= n);
    const int cl = activecol ? lane : 1;            // clamped column index for LDS reads

    // Reference-faithful broken JV (minv/way never persisted in the python):
    // each inner step is a fresh argmin of the CURRENT row's reduced costs over
    // free columns; augment collapses to p[j_final] = i.
    // lane r holds u[r] (f64); lane j holds v[j] (f64), used[j], p[j].
    // Comparison keys are f32 (monotone f64->f32), updates stay exact f64.
    double u_r = 0.0, v_j = 0.0;
    int p_j = 0;

    for (int i = 1; i <= n; ++i) {
      if (lane == 0) p_j = i;                       // p[0] = i
      int j0 = 0, i0 = i;
      bool used = false, row_used = false;
      float cst = costL[(i0 - 1) * 32 + (cl - 1)];  // prefetched row i
      double u0 = __shfl(u_r, i0);
      while (true) {
        used = used || (lane == j0);                // used[j0] = True
        row_used = row_used || (lane == i0);        // rows {i} ∪ {p[j]: j used}
        double cur = (double)cst - u0 - v_j;
        bool act = activecol && !used;
        float m = act ? (float)cur : FINF;
        float delta_f = wave_min_bcast(m);
        uint64_t tie = __ballot(m == delta_f);      // inactive lanes hold FINF != delta
        int j1 = __ffsll((unsigned long long)tie) - 1;  // numpy first-index tie-break
        double delta = __shfl(cur, j1);             // exact f64 min for updates
        int pj1 = __shfl(p_j, j1);
        if (row_used) u_r += delta;                 // u[p[used]] += delta
        if (used) v_j -= delta;                     // v[used] -= delta
        if (pj1 == 0) {                             // p[j1]==0 -> p[j1]=i; done
          if (lane == j1) p_j = i;
          break;
        }
        j0 = j1; i0 = pj1;
        cst = costL[(i0 - 1) * 32 + (cl - 1)];      // prefetch next row (overlaps shfl)
        u0 = __shfl(u_r, i0);                       // post-update u[i0]
      }
    }

    // assigned cost sum: column j matched to row p[j]  ->  cost[p[j]-1][j-1]
    int pj = p_j < 1 ? 1 : p_j;
    float a = activecol ? costL[(pj - 1) * 32 + (cl - 1)] : 0.f;
#pragma unroll
    for (int off = 32; off; off >>= 1) {
      a += __shfl_xor(a, off);
      clfpart += __shfl_xor(clfpart, off);
    }
    if (lane == 0) {
      part[b * 3 + 0] = a;
      part[b * 3 + 1] = clfpart;
      part[b * 3 + 2] = (float)n;
    }
  }
}

__global__ void finalize_kernel(const float* __restrict__ part, float* __restrict__ out) {
  const int lane = threadIdx.x;   // 64 threads, 1 block: deterministic fixed-order reduce
  double cs = 0.0, ls = 0.0, ns = 0.0;
  for (int i = lane; i < NB; i += 64) {
    cs += (double)part[i * 3 + 0];
    ls += (double)part[i * 3 + 1];
    ns += (double)part[i * 3 + 2];
  }
#pragma unroll
  for (int off = 32; off; off >>= 1) {
    cs += __shfl_xor(cs, off);
    ls += __shfl_xor(ls, off);
    ns += __shfl_xor(ns, off);
  }
  if (lane == 0) {
    out[0] = (float)(cs / (ns * 256.0));  // / sum(point_masks) = 256 * sum(n)
    out[1] = (float)(ls / ns);            // / sum(line_masks)
  }
}

extern "C" void kernel_launch(void* const* d_in, const int* in_sizes, int n_in,
                              void* d_out, int out_size, void* d_ws, size_t ws_size,
                              hipStream_t stream) {
  const float* pred = (const float*)d_in[0];   // point_pos_pred [512,32,256,2] f32
  const float* prob = (const float*)d_in[1];   // line_prob_pred [512,32,2] f32
  const float* tgt  = (const float*)d_in[2];   // target_pos [512,32,256,2] f32
  const float* lm   = (const float*)d_in[3];   // line_masks [512,32] f32
  const int*   clf  = (const int*)d_in[4];     // clf_line [512,32] i32
  float* part = (float*)d_ws;                  // [512][3] f32 partials

  hungarian_loss_kernel<<<NB, 256, 0, stream>>>(pred, prob, tgt, lm, clf, part);
  finalize_kernel<<<1, 64, 0, stream>>>(part, (float*)d_out);
}